// Round 5
// baseline (165.033 us; speedup 1.0000x reference)
//
#include <hip/hip_runtime.h>

#define NROWS 262144
#define NE 5
#define CAP 57344                // per-expert capacity (mean 52429, sigma~205)
#define TM 128                   // rows per mlp block = 4 waves x 32
#define TILES (CAP / TM)         // 448

typedef __attribute__((ext_vector_type(8))) short short8;
typedef __attribute__((ext_vector_type(8))) unsigned short ushort8;
typedef __attribute__((ext_vector_type(4))) float f32x4;
// 16B vector load with only 4B alignment guarantee
typedef __attribute__((ext_vector_type(4), aligned(4))) float f32x4u;

__device__ __forceinline__ unsigned short f2bf(float x) {
  unsigned u = __float_as_uint(x);
  u += 0x7FFF + ((u >> 16) & 1);   // round-to-nearest-even
  return (unsigned short)(u >> 16);
}

// ---------------- kernel 1: convert W1,W2 to transposed bf16 -----------------
// Wt[e][j][k] = W[e][k][j]  (MFMA B-fragments become contiguous 16B reads)
__global__ __launch_bounds__(256) void convw(const float* __restrict__ W1,
                                             const float* __restrict__ W2,
                                             unsigned short* __restrict__ Wt1,
                                             unsigned short* __restrict__ Wt2) {
  int idx = blockIdx.x * 256 + threadIdx.x;       // 0 .. 163839
  int which = idx / 81920;
  int rem = idx % 81920;
  int e = rem / 16384;
  int jk = rem % 16384;
  int j = jk / 128;
  int k = jk % 128;
  const float* W = which ? W2 : W1;
  unsigned short* Wt = which ? Wt2 : Wt1;
  Wt[e * 16384 + j * 128 + k] = f2bf(W[e * 16384 + k * 128 + j]);
}

// ---- kernel 2: classify rows AND compact f (bf16) + t into expert buckets ---
// Streaming: read x coalesced once, scatter-WRITE compacted rows (no read stalls).
__global__ __launch_bounds__(256) void classify_compact(
    const float* __restrict__ x,
    int* __restrict__ bucket, float* __restrict__ tcb,
    unsigned short* __restrict__ xc, int* __restrict__ cnt) {
  int r0 = blockIdx.x * 64;                       // 64 rows per block
  int tid = threadIdx.x;

  __shared__ int dstS[64];
  __shared__ int lc[NE];
  __shared__ int lb[NE];
  if (tid < NE) lc[tid] = 0;
  __syncthreads();

  if (tid < 64) {
    int r = r0 + tid;
    float t = x[(size_t)r * 129];
    int e = (t >= 0.2f) + (t >= 0.4f) + (t >= 0.6f) + (t >= 0.8f);
    int lpos = atomicAdd(&lc[e], 1);
    dstS[tid] = (e << 26) | lpos;
    // stash t for later write (reuse lb barrier); write after dst known
    // (store t in register via shared round trip below)
    ((float*)dstS)[0];  // no-op
    // keep t in LDS alongside: pack into separate array
    // (use a second shared array)
    __shared__ float tS_[64];
    tS_[tid] = t;
  }
  __syncthreads();
  if (tid < NE) lb[tid] = atomicAdd(&cnt[tid], lc[tid]);
  __syncthreads();

  __shared__ float tS_[64];   // same instance as above (shadow decl trick not valid)
  if (tid < 64) {
    int e = dstS[tid] >> 26;
    int lpos = dstS[tid] & ((1 << 26) - 1);
    int dst = min(lb[e] + lpos, CAP - 1);
    dstS[tid] = (e << 26) | dst;
    bucket[(size_t)e * CAP + dst] = r0 + tid;
    tcb[(size_t)e * CAP + dst] = tS_[tid];
  }
  __syncthreads();

  // phase 2: copy f rows, 4 threads per row, 32 floats each -> 64B bf16
  int row = tid >> 2;
  int sub = tid & 3;
  int packed = dstS[row];
  int e = packed >> 26;
  int dst = packed & ((1 << 26) - 1);
  const float* src = x + (size_t)(r0 + row) * 129 + 1 + sub * 32;
  unsigned short* d = xc + (size_t)e * CAP * 128 + (size_t)dst * 128 + sub * 32;

  f32x4u v[8];
#pragma unroll
  for (int q = 0; q < 8; ++q) v[q] = *(const f32x4u*)(src + q * 4);
#pragma unroll
  for (int c = 0; c < 4; ++c) {
    ushort8 p;
#pragma unroll
    for (int j = 0; j < 4; ++j) {
      p[j]     = f2bf(v[2 * c][j]);
      p[4 + j] = f2bf(v[2 * c + 1][j]);
    }
    *(ushort8*)(d + c * 8) = p;
  }
}

// ---- kernel 3: per-expert MLP; A-frags direct from compacted bf16 tile -----
__global__ __launch_bounds__(256, 4) void mlp(
    const unsigned short* __restrict__ xc,
    const unsigned short* __restrict__ Wt1, const float* __restrict__ tw1, const float* __restrict__ b1,
    const unsigned short* __restrict__ Wt2, const float* __restrict__ tw2, const float* __restrict__ b2,
    const float* __restrict__ W3, const float* __restrict__ tw3, const float* __restrict__ b3,
    const int* __restrict__ bucket, const float* __restrict__ tc, const int* __restrict__ cnt,
    float* __restrict__ out) {
  int e = blockIdx.x / TILES;
  int it = blockIdx.x % TILES;
  int n = min(cnt[e], CAP);
  int i0 = it * TM;
  if (i0 >= n) return;

  __shared__ unsigned short hbuf[4][32 * 128];   // 8 KB per wave, swizzled

  int tid  = threadIdx.x;
  int wave = tid >> 6;
  int lane = tid & 63;
  int lr = lane & 15;        // A-row within 16-group / D-col within ct
  int lq = lane >> 4;        // k-quad / D-row-quad
  int rbase = i0 + wave * 32;

  const int* bk = bucket + (size_t)e * CAP;
  const float* tce = tc + (size_t)e * CAP;
  const unsigned short* xce = xc + (size_t)e * CAP * 128;

  // 32 bucket positions' row-ids + t for this wave, coalesced (dup lanes>=32)
  int clampIdx = min(rbase + (lane & 31), n - 1);
  int rI = bk[clampIdx];
  float tv = tce[clampIdx];

  // A fragments directly from the contiguous bf16 tile (8 independent loads)
  int row0 = min(rbase + lr, n - 1);
  int row1 = min(rbase + 16 + lr, n - 1);
  short8 a0[4], a1[4];
#pragma unroll
  for (int ks = 0; ks < 4; ++ks) {
    a0[ks] = *(const short8*)(xce + (size_t)row0 * 128 + ks * 32 + lq * 8);
    a1[ks] = *(const short8*)(xce + (size_t)row1 * 128 + ks * 32 + lq * 8);
  }

  // t values and output row ids for the D-rows this lane owns, via shuffle
  float t0[4], t1[4];
  int ro0[4], ro1[4];
#pragma unroll
  for (int rr = 0; rr < 4; ++rr) {
    t0[rr] = __shfl(tv, lq * 4 + rr);
    t1[rr] = __shfl(tv, 16 + lq * 4 + rr);
    ro0[rr] = __shfl(rI, lq * 4 + rr);
    ro1[rr] = __shfl(rI, 16 + lq * 4 + rr);
  }

  char* hp = (char*)hbuf[wave];
  const unsigned short* W1e = Wt1 + e * 16384;

  // ===== layer 1: h1 = relu(f @ W1 + t*tw1 + b1) -> per-wave LDS (swizzled) =
#pragma unroll
  for (int ct = 0; ct < 8; ++ct) {
    short8 b[4];
#pragma unroll
    for (int ks = 0; ks < 4; ++ks)
      b[ks] = *(const short8*)(W1e + (ct * 16 + lr) * 128 + ks * 32 + lq * 8);
    f32x4 acc0 = {0.f, 0.f, 0.f, 0.f};
    f32x4 acc1 = {0.f, 0.f, 0.f, 0.f};
#pragma unroll
    for (int ks = 0; ks < 4; ++ks) {
      acc0 = __builtin_amdgcn_mfma_f32_16x16x32_bf16(a0[ks], b[ks], acc0, 0, 0, 0);
      acc1 = __builtin_amdgcn_mfma_f32_16x16x32_bf16(a1[ks], b[ks], acc1, 0, 0, 0);
    }
    int col = ct * 16 + lr;
    float twv = tw1[e * 128 + col];
    float bv  = b1[e * 128 + col];
#pragma unroll
    for (int rr = 0; rr < 4; ++rr) {
      int r0_ = lq * 4 + rr;
      int r1_ = r0_ + 16;
      float v0 = fmaxf(acc0[rr] + t0[rr] * twv + bv, 0.f);
      float v1 = fmaxf(acc1[rr] + t1[rr] * twv + bv, 0.f);
      *(unsigned short*)(hp + ((r0_ * 256 + col * 2) ^ ((r0_ & 7) << 4))) = f2bf(v0);
      *(unsigned short*)(hp + ((r1_ * 256 + col * 2) ^ ((r1_ & 7) << 4))) = f2bf(v1);
    }
  }

  // wave-local LDS fence (rule 18)
  asm volatile("s_waitcnt lgkmcnt(0)" ::: "memory");
  __builtin_amdgcn_sched_barrier(0);

#pragma unroll
  for (int ks = 0; ks < 4; ++ks) {
    int off0 = (lr * 256 + ks * 64 + lq * 16) ^ ((lr & 7) << 4);
    int off1 = ((16 + lr) * 256 + ks * 64 + lq * 16) ^ ((lr & 7) << 4);
    a0[ks] = *(const short8*)(hp + off0);
    a1[ks] = *(const short8*)(hp + off1);
  }

  // ===== layer 2 + fused layer 3: o += relu(h1@W2 + t*tw2 + b2) * W3 ========
  const unsigned short* W2e = Wt2 + e * 16384;
  const float* W3e = W3 + e * 128;
  float o0[4] = {0.f, 0.f, 0.f, 0.f};
  float o1[4] = {0.f, 0.f, 0.f, 0.f};
#pragma unroll
  for (int ct = 0; ct < 8; ++ct) {
    short8 b[4];
#pragma unroll
    for (int ks = 0; ks < 4; ++ks)
      b[ks] = *(const short8*)(W2e + (ct * 16 + lr) * 128 + ks * 32 + lq * 8);
    f32x4 acc0 = {0.f, 0.f, 0.f, 0.f};
    f32x4 acc1 = {0.f, 0.f, 0.f, 0.f};
#pragma unroll
    for (int ks = 0; ks < 4; ++ks) {
      acc0 = __builtin_amdgcn_mfma_f32_16x16x32_bf16(a0[ks], b[ks], acc0, 0, 0, 0);
      acc1 = __builtin_amdgcn_mfma_f32_16x16x32_bf16(a1[ks], b[ks], acc1, 0, 0, 0);
    }
    int col = ct * 16 + lr;
    float twv = tw2[e * 128 + col];
    float bv  = b2[e * 128 + col];
    float w3v = W3e[col];
#pragma unroll
    for (int rr = 0; rr < 4; ++rr) {
      float v0 = fmaxf(acc0[rr] + t0[rr] * twv + bv, 0.f);
      float v1 = fmaxf(acc1[rr] + t1[rr] * twv + bv, 0.f);
      o0[rr] += v0 * w3v;
      o1[rr] += v1 * w3v;
    }
  }

  // reduce over the 16 cols held across lanes lr=0..15 (xor stays in-group)
#pragma unroll
  for (int rr = 0; rr < 4; ++rr) {
    float s0 = o0[rr], s1 = o1[rr];
    s0 += __shfl_xor(s0, 1);  s1 += __shfl_xor(s1, 1);
    s0 += __shfl_xor(s0, 2);  s1 += __shfl_xor(s1, 2);
    s0 += __shfl_xor(s0, 4);  s1 += __shfl_xor(s1, 4);
    s0 += __shfl_xor(s0, 8);  s1 += __shfl_xor(s1, 8);
    o0[rr] = s0;  o1[rr] = s1;
  }

  if (lr == 0) {
    float tw3v = tw3[e];
    float b3v  = b3[e];
#pragma unroll
    for (int rr = 0; rr < 4; ++rr) {
      if (rbase + lq * 4 + rr < n)
        out[ro0[rr]] = o0[rr] + t0[rr] * tw3v + b3v;
      if (rbase + 16 + lq * 4 + rr < n)
        out[ro1[rr]] = o1[rr] + t1[rr] * tw3v + b3v;
    }
  }
}

extern "C" void kernel_launch(void* const* d_in, const int* in_sizes, int n_in,
                              void* d_out, int out_size, void* d_ws, size_t ws_size,
                              hipStream_t stream) {
  const float* x   = (const float*)d_in[0];
  const float* W1  = (const float*)d_in[1];
  const float* tw1 = (const float*)d_in[2];
  const float* b1  = (const float*)d_in[3];
  const float* W2  = (const float*)d_in[4];
  const float* tw2 = (const float*)d_in[5];
  const float* b2  = (const float*)d_in[6];
  const float* W3  = (const float*)d_in[7];
  const float* tw3 = (const float*)d_in[8];
  const float* b3  = (const float*)d_in[9];
  float* out = (float*)d_out;

  char* ws = (char*)d_ws;
  int*   cnt    = (int*)ws;                                        // 256 B
  int*   bucket = (int*)(ws + 256);                                // 5*CAP*4
  float* tcmp   = (float*)(ws + 256 + (size_t)NE * CAP * 4);       // 5*CAP*4
  unsigned short* xc = (unsigned short*)(ws + 256 + (size_t)NE * CAP * 8);  // 5*CAP*256 B
  unsigned short* Wt1 = (unsigned short*)(ws + 256 + (size_t)NE * CAP * 8
                                          + (size_t)NE * CAP * 256);
  unsigned short* Wt2 = Wt1 + NE * 16384;

  hipMemsetAsync(cnt, 0, NE * sizeof(int), stream);
  convw<<<640, 256, 0, stream>>>(W1, W2, Wt1, Wt2);
  classify_compact<<<NROWS / 64, 256, 0, stream>>>(x, bucket, tcmp, xc, cnt);
  mlp<<<NE * TILES, 256, 0, stream>>>(xc, Wt1, tw1, b1, Wt2, tw2, b2, W3, tw3, b3,
                                      bucket, tcmp, cnt, out);
}

// Round 6
// 123.219 us; speedup vs baseline: 1.3393x; 1.3393x over previous
//
#include <hip/hip_runtime.h>

#define NROWS 262144
#define NE 5
#define RPB 128                  // rows per block (4 waves x 32)
#define NBLK (NROWS / RPB)       // 2048

typedef __attribute__((ext_vector_type(8))) short short8;
typedef __attribute__((ext_vector_type(4))) float f32x4;

__device__ __forceinline__ unsigned short f2bf(float x) {
  unsigned u = __float_as_uint(x);
  u += 0x7FFF + ((u >> 16) & 1);   // round-to-nearest-even
  return (unsigned short)(u >> 16);
}

// ---------------- kernel 1: convert W1,W2 to transposed bf16 -----------------
// Wt[e][j][k] = W[e][k][j]  (MFMA B-fragments become contiguous 16B reads)
__global__ __launch_bounds__(256) void convw(const float* __restrict__ W1,
                                             const float* __restrict__ W2,
                                             unsigned short* __restrict__ Wt1,
                                             unsigned short* __restrict__ Wt2) {
  int idx = blockIdx.x * 256 + threadIdx.x;       // 0 .. 163839
  int which = idx / 81920;
  int rem = idx % 81920;
  int e = rem / 16384;
  int jk = rem % 16384;
  int j = jk / 128;
  int k = jk % 128;
  const float* W = which ? W2 : W1;
  unsigned short* Wt = which ? Wt2 : Wt1;
  Wt[e * 16384 + j * 128 + k] = f2bf(W[e * 16384 + k * 128 + j]);
}

// -------- kernel 2: FUSED stage + block-local expert sort + 3-layer MLP ------
__global__ __launch_bounds__(256, 3) void fused(
    const float* __restrict__ x,
    const unsigned short* __restrict__ Wt1, const float* __restrict__ tw1, const float* __restrict__ b1,
    const unsigned short* __restrict__ Wt2, const float* __restrict__ tw2, const float* __restrict__ b2,
    const float* __restrict__ W3, const float* __restrict__ tw3, const float* __restrict__ b3,
    float* __restrict__ out) {
  __shared__ unsigned short ftile[RPB * 128];   // 32 KB, swizzled; reused for h1
  __shared__ float tS[RPB];
  __shared__ int permS[RPB];
  __shared__ int cntS[NE];
  __shared__ int offS[NE];
  __shared__ int tileE[8], tileB[8], tileN[8];
  __shared__ int numTilesS;

  int tid = threadIdx.x;
  int r0 = blockIdx.x * RPB;
  char* fp = (char*)ftile;

  if (tid < NE) cntS[tid] = 0;

  // ---- stage: 128x129 floats, 4128 float4s, base is ALWAYS 16B-aligned
  // (r0*129*4 = blockIdx*66048, 66048 % 16 == 0). Fully coalesced loads,
  // then elementwise scatter (magic div by 129) into swizzled bf16 tile.
  const f32x4* xv = (const f32x4*)(x + (size_t)r0 * 129);
#pragma unroll
  for (int ch = 0; ch < 2; ++ch) {
    const int it0 = ch ? 9 : 0;
    const int nit = ch ? 8 : 9;
    f32x4 stg[9];
#pragma unroll
    for (int q = 0; q < 9; ++q) {
      if (q < nit) {
        int v = (it0 + q) * 256 + tid;
        if (v < 4128) stg[q] = xv[v];
      }
    }
#pragma unroll
    for (int q = 0; q < 9; ++q) {
      if (q < nit) {
        int v = (it0 + q) * 256 + tid;
        if (v < 4128) {
#pragma unroll
          for (int j = 0; j < 4; ++j) {
            int l = v * 4 + j;                              // 0..16511
            int row = (int)(((unsigned)l * 65028u) >> 23);  // l / 129
            int c = l - row * 129;
            float val = stg[q][j];
            if (c == 0) {
              tS[row] = val;                                // t column
            } else {
              int cc = c - 1;
              int off = (row * 256 + cc * 2) ^ ((row & 7) << 4);
              *(unsigned short*)(fp + off) = f2bf(val);
            }
          }
        }
      }
    }
  }
  __syncthreads();

  // ---- block-local expert sort: perm[] groups row slots by expert ----
  int myE = 0, myL = 0;
  if (tid < RPB) {
    float t = tS[tid];
    myE = (t >= 0.2f) + (t >= 0.4f) + (t >= 0.6f) + (t >= 0.8f);
    myL = atomicAdd(&cntS[myE], 1);
  }
  __syncthreads();
  if (tid == 0) {
    int off = 0, nt = 0;
    for (int e = 0; e < NE; ++e) {
      offS[e] = off;
      int ne = cntS[e];
      for (int s = 0; s < ne; s += 32) {
        tileE[nt] = e; tileB[nt] = off + s; tileN[nt] = min(32, ne - s); ++nt;
      }
      off += ne;
    }
    numTilesS = nt;            // 4..8 tiles
  }
  __syncthreads();
  if (tid < RPB) permS[offS[myE] + myL] = tid;
  __syncthreads();

  int numTiles = numTilesS;
  int wave = tid >> 6;
  int lane = tid & 63;
  int lr = lane & 15;          // A-row-in-16 / D-col / B-row
  int lq = lane >> 4;          // k-quad / D-row-quad

  // each wave owns whole tiles; tile rows (via perm bijection) are private
  // to the owning wave -> no __syncthreads in this loop.
  for (int ti = wave; ti < numTiles; ti += 4) {
    int e   = tileE[ti];
    int tb  = tileB[ti];
    int tn  = tileN[ti];

    int p0 = permS[tb + min(lr, tn - 1)];
    int p1 = permS[tb + min(16 + lr, tn - 1)];

    short8 a0[4], a1[4];
#pragma unroll
    for (int ks = 0; ks < 4; ++ks) {
      int off0 = (p0 * 256 + ks * 64 + lq * 16) ^ ((p0 & 7) << 4);
      int off1 = (p1 * 256 + ks * 64 + lq * 16) ^ ((p1 & 7) << 4);
      a0[ks] = *(const short8*)(fp + off0);
      a1[ks] = *(const short8*)(fp + off1);
    }

    int pd0[4], pd1[4];
    float t0[4], t1[4];
#pragma unroll
    for (int rr = 0; rr < 4; ++rr) {
      pd0[rr] = permS[tb + min(lq * 4 + rr, tn - 1)];
      pd1[rr] = permS[tb + min(16 + lq * 4 + rr, tn - 1)];
      t0[rr] = tS[pd0[rr]];
      t1[rr] = tS[pd1[rr]];
    }

    const unsigned short* W1e = Wt1 + e * 16384;

    // ===== layer 1: h1 = relu(f@W1 + t*tw1 + b1) -> IN PLACE over f rows ====
    // (h1 slot s writes physical row perm[tb+s]; padded slots masked so the
    //  clamped row tn-1 is never clobbered. All f reads of this tile complete
    //  before any h1 write by MFMA dataflow.)
#pragma unroll
    for (int ct = 0; ct < 8; ++ct) {
      short8 b[4];
#pragma unroll
      for (int ks = 0; ks < 4; ++ks)
        b[ks] = *(const short8*)(W1e + (ct * 16 + lr) * 128 + ks * 32 + lq * 8);
      f32x4 acc0 = {0.f, 0.f, 0.f, 0.f};
      f32x4 acc1 = {0.f, 0.f, 0.f, 0.f};
#pragma unroll
      for (int ks = 0; ks < 4; ++ks) {
        acc0 = __builtin_amdgcn_mfma_f32_16x16x32_bf16(a0[ks], b[ks], acc0, 0, 0, 0);
        acc1 = __builtin_amdgcn_mfma_f32_16x16x32_bf16(a1[ks], b[ks], acc1, 0, 0, 0);
      }
      int col = ct * 16 + lr;
      float twv = tw1[e * 128 + col];
      float bv  = b1[e * 128 + col];
#pragma unroll
      for (int rr = 0; rr < 4; ++rr) {
        float v0 = fmaxf(acc0[rr] + t0[rr] * twv + bv, 0.f);
        float v1 = fmaxf(acc1[rr] + t1[rr] * twv + bv, 0.f);
        if (lq * 4 + rr < tn)
          *(unsigned short*)(fp + ((pd0[rr] * 256 + col * 2) ^ ((pd0[rr] & 7) << 4))) = f2bf(v0);
        if (16 + lq * 4 + rr < tn)
          *(unsigned short*)(fp + ((pd1[rr] * 256 + col * 2) ^ ((pd1[rr] & 7) << 4))) = f2bf(v1);
      }
    }

    // wave-local LDS fence between h1 writes and h1 reads (rule 18)
    asm volatile("s_waitcnt lgkmcnt(0)" ::: "memory");
    __builtin_amdgcn_sched_barrier(0);

#pragma unroll
    for (int ks = 0; ks < 4; ++ks) {
      int off0 = (p0 * 256 + ks * 64 + lq * 16) ^ ((p0 & 7) << 4);
      int off1 = (p1 * 256 + ks * 64 + lq * 16) ^ ((p1 & 7) << 4);
      a0[ks] = *(const short8*)(fp + off0);
      a1[ks] = *(const short8*)(fp + off1);
    }

    // ===== layer 2 + fused layer 3: o += relu(h1@W2 + t*tw2 + b2) * W3 ======
    const unsigned short* W2e = Wt2 + e * 16384;
    const float* W3e = W3 + e * 128;
    float o0[4] = {0.f, 0.f, 0.f, 0.f};
    float o1[4] = {0.f, 0.f, 0.f, 0.f};
#pragma unroll
    for (int ct = 0; ct < 8; ++ct) {
      short8 b[4];
#pragma unroll
      for (int ks = 0; ks < 4; ++ks)
        b[ks] = *(const short8*)(W2e + (ct * 16 + lr) * 128 + ks * 32 + lq * 8);
      f32x4 acc0 = {0.f, 0.f, 0.f, 0.f};
      f32x4 acc1 = {0.f, 0.f, 0.f, 0.f};
#pragma unroll
      for (int ks = 0; ks < 4; ++ks) {
        acc0 = __builtin_amdgcn_mfma_f32_16x16x32_bf16(a0[ks], b[ks], acc0, 0, 0, 0);
        acc1 = __builtin_amdgcn_mfma_f32_16x16x32_bf16(a1[ks], b[ks], acc1, 0, 0, 0);
      }
      int col = ct * 16 + lr;
      float twv = tw2[e * 128 + col];
      float bv  = b2[e * 128 + col];
      float w3v = W3e[col];
#pragma unroll
      for (int rr = 0; rr < 4; ++rr) {
        float v0 = fmaxf(acc0[rr] + t0[rr] * twv + bv, 0.f);
        float v1 = fmaxf(acc1[rr] + t1[rr] * twv + bv, 0.f);
        o0[rr] += v0 * w3v;
        o1[rr] += v1 * w3v;
      }
    }

    // reduce over the 16 cols held across lanes lr=0..15 (xor stays in-group)
#pragma unroll
    for (int rr = 0; rr < 4; ++rr) {
      float s0 = o0[rr], s1 = o1[rr];
      s0 += __shfl_xor(s0, 1);  s1 += __shfl_xor(s1, 1);
      s0 += __shfl_xor(s0, 2);  s1 += __shfl_xor(s1, 2);
      s0 += __shfl_xor(s0, 4);  s1 += __shfl_xor(s1, 4);
      s0 += __shfl_xor(s0, 8);  s1 += __shfl_xor(s1, 8);
      o0[rr] = s0;  o1[rr] = s1;
    }

    if (lr == 0) {
      float tw3v = tw3[e];
      float b3v  = b3[e];
#pragma unroll
      for (int rr = 0; rr < 4; ++rr) {
        if (lq * 4 + rr < tn)
          out[r0 + pd0[rr]] = o0[rr] + t0[rr] * tw3v + b3v;
        if (16 + lq * 4 + rr < tn)
          out[r0 + pd1[rr]] = o1[rr] + t1[rr] * tw3v + b3v;
      }
    }
  }
}

extern "C" void kernel_launch(void* const* d_in, const int* in_sizes, int n_in,
                              void* d_out, int out_size, void* d_ws, size_t ws_size,
                              hipStream_t stream) {
  const float* x   = (const float*)d_in[0];
  const float* W1  = (const float*)d_in[1];
  const float* tw1 = (const float*)d_in[2];
  const float* b1  = (const float*)d_in[3];
  const float* W2  = (const float*)d_in[4];
  const float* tw2 = (const float*)d_in[5];
  const float* b2  = (const float*)d_in[6];
  const float* W3  = (const float*)d_in[7];
  const float* tw3 = (const float*)d_in[8];
  const float* b3  = (const float*)d_in[9];
  float* out = (float*)d_out;

  unsigned short* Wt1 = (unsigned short*)d_ws;      // 5*16384 bf16 = 160 KB
  unsigned short* Wt2 = Wt1 + NE * 16384;           // 160 KB

  convw<<<640, 256, 0, stream>>>(W1, W2, Wt1, Wt2);
  fused<<<NBLK, 256, 0, stream>>>(x, Wt1, tw1, b1, Wt2, tw2, b2, W3, tw3, b3, out);
}

// Round 7
// 112.169 us; speedup vs baseline: 1.4713x; 1.0985x over previous
//
#include <hip/hip_runtime.h>

#define NROWS 262144
#define NE 5
#define CAP 57344                 // per-expert capacity (mean 52429, ~24 sigma)
#define BPE 51                    // mlp blocks per expert (5*51 = 255 blocks)
#define CHUNK 256                 // rows per mlp block-iteration (8 waves x 32)

typedef __attribute__((ext_vector_type(8))) short short8;
typedef __attribute__((ext_vector_type(8))) unsigned short ushort8;
typedef __attribute__((ext_vector_type(4))) float f32x4;

__device__ __forceinline__ unsigned short f2bf(float x) {
  unsigned u = __float_as_uint(x);
  u += 0x7FFF + ((u >> 16) & 1);   // round-to-nearest-even
  return (unsigned short)(u >> 16);
}

// ---- kernel 1: W1,W2 -> bf16 in the SWIZZLED LDS-image layout --------------
// Per expert: 16384 shorts for W1 then 16384 for W2.
// Element (col=j, k) lives at byte ((j*256 + k*2) ^ ((j&7)<<4)) within its layer
// so the mlp can memcpy the block into LDS and read conflict-free b128 frags.
__global__ __launch_bounds__(256) void convw(const float* __restrict__ W1,
                                             const float* __restrict__ W2,
                                             unsigned short* __restrict__ Wswz) {
  int idx = blockIdx.x * 256 + threadIdx.x;       // 0 .. 163839
  int which = idx / 81920;
  int rem = idx % 81920;
  int e = rem / 16384;
  int jk = rem % 16384;
  int j = jk >> 7;                // output col
  int k = jk & 127;               // k index
  const float* W = which ? W2 : W1;
  int byteoff = (j * 256 + k * 2) ^ ((j & 7) << 4);
  Wswz[(size_t)e * 32768 + which * 16384 + (byteoff >> 1)] =
      f2bf(W[(size_t)e * 16384 + k * 128 + j]);
}

// ---- kernel 2: classify rows, compact f(bf16)+t+rowid into expert buckets --
// 64 rows/block. x chunk is 8256 floats = 2064 float4, 16B-aligned (66048%16==0).
__global__ __launch_bounds__(256) void classify_compact(
    const float* __restrict__ x,
    unsigned short* __restrict__ xc, float* __restrict__ tcb,
    int* __restrict__ ridb, int* __restrict__ cnt) {
  __shared__ float xf[64 * 129];    // 33 KB raw staging
  __shared__ int dstS[64];
  __shared__ int lcS[NE];
  __shared__ int gbS[NE];

  int tid = threadIdx.x;
  int r0 = blockIdx.x * 64;

  const f32x4* xv = (const f32x4*)(x + (size_t)r0 * 129);
  f32x4* xfv = (f32x4*)xf;
#pragma unroll
  for (int q = 0; q < 8; ++q) xfv[q * 256 + tid] = xv[q * 256 + tid];
  if (tid < 16) xfv[2048 + tid] = xv[2048 + tid];
  if (tid < NE) lcS[tid] = 0;
  __syncthreads();

  int myE = 0, myL = 0;
  if (tid < 64) {
    float t = xf[tid * 129];
    myE = (t >= 0.2f) + (t >= 0.4f) + (t >= 0.6f) + (t >= 0.8f);
    myL = atomicAdd(&lcS[myE], 1);
  }
  __syncthreads();
  if (tid < NE) gbS[tid] = atomicAdd(&cnt[tid], lcS[tid]);
  __syncthreads();
  if (tid < 64) {
    int dst = min(gbS[myE] + myL, CAP - 1);
    int d = myE * CAP + dst;
    dstS[tid] = d;
    tcb[d] = xf[tid * 129];
    ridb[d] = r0 + tid;
  }
  __syncthreads();

  // copy f rows: 4 threads/row, 32 floats each -> 64 B bf16 (256 B/row contig)
  int row = tid >> 2;
  int sub = tid & 3;
  int d = dstS[row];
  const float* src = xf + row * 129 + 1 + sub * 32;
  ushort8* dp = (ushort8*)(xc + (size_t)d * 128 + sub * 32);
#pragma unroll
  for (int c = 0; c < 4; ++c) {
    ushort8 p;
#pragma unroll
    for (int j = 0; j < 8; ++j) p[j] = f2bf(src[c * 8 + j]);
    dp[c] = p;
  }
}

// ---- kernel 3: per-expert MLP, weights resident in LDS ---------------------
// 512 threads = 8 waves (2/SIMD), LDS = 64KB weights + 64KB h1 -> 1 block/CU.
__global__ __launch_bounds__(512, 2) void mlp(
    const unsigned short* __restrict__ xc, const float* __restrict__ tcb,
    const int* __restrict__ ridb, const int* __restrict__ cnt,
    const unsigned short* __restrict__ Wswz,
    const float* __restrict__ tw1, const float* __restrict__ b1,
    const float* __restrict__ tw2, const float* __restrict__ b2,
    const float* __restrict__ W3, const float* __restrict__ tw3,
    const float* __restrict__ b3, float* __restrict__ out) {
  __shared__ unsigned short wl[32768];          // 64 KB: W1 swz | W2 swz
  __shared__ unsigned short h1[8][32 * 128];    // 8 KB per wave, swizzled

  int tid = threadIdx.x;
  int e = blockIdx.x / BPE;
  int bi = blockIdx.x % BPE;
  int n = min(cnt[e], CAP);

  // stage this expert's weights into LDS (4096 ushort8, 8 per thread)
  {
    const ushort8* wsrc = (const ushort8*)(Wswz + (size_t)e * 32768);
    ushort8* wdst = (ushort8*)wl;
#pragma unroll
    for (int i = 0; i < 8; ++i) wdst[i * 512 + tid] = wsrc[i * 512 + tid];
  }
  __syncthreads();

  int wave = tid >> 6;
  int lane = tid & 63;
  int lr = lane & 15;          // A-row-in-16 / D-col / B-col-in-16
  int lq = lane >> 4;          // k-quad / D-row-quad

  const char* wp1 = (const char*)wl;
  const char* wp2 = (const char*)wl + 32768;
  char* hp = (char*)h1[wave];
  const unsigned short* xce = xc + (size_t)e * CAP * 128;
  const float* tce = tcb + (size_t)e * CAP;
  const int* ride = ridb + (size_t)e * CAP;

  int nchunk = (n + CHUNK - 1) / CHUNK;
  for (int c = bi; c < nchunk; c += BPE) {
    int base = c * CHUNK + wave * 32;
    if (base >= n) continue;

    // 32 t values + row ids, coalesced (dup on lanes>=32)
    int ci = min(base + (lane & 31), n - 1);
    float tv = tce[ci];
    int rv = ride[ci];

    // A fragments from contiguous bf16 tile (8 independent 16B loads)
    int row0 = min(base + lr, n - 1);
    int row1 = min(base + 16 + lr, n - 1);
    short8 a0[4], a1[4];
#pragma unroll
    for (int ks = 0; ks < 4; ++ks) {
      a0[ks] = *(const short8*)(xce + (size_t)row0 * 128 + ks * 32 + lq * 8);
      a1[ks] = *(const short8*)(xce + (size_t)row1 * 128 + ks * 32 + lq * 8);
    }

    float t0[4], t1[4];
    int ro0[4], ro1[4];
#pragma unroll
    for (int rr = 0; rr < 4; ++rr) {
      t0[rr] = __shfl(tv, lq * 4 + rr);
      t1[rr] = __shfl(tv, 16 + lq * 4 + rr);
      ro0[rr] = __shfl(rv, lq * 4 + rr);
      ro1[rr] = __shfl(rv, 16 + lq * 4 + rr);
    }

    // ===== layer 1: h1 = relu(f@W1 + t*tw1 + b1) -> per-wave LDS ===========
#pragma unroll
    for (int ct = 0; ct < 8; ++ct) {
      int col = ct * 16 + lr;
      short8 b[4];
#pragma unroll
      for (int ks = 0; ks < 4; ++ks) {
        int bo = (col * 256 + ks * 64 + lq * 16) ^ ((lr & 7) << 4);
        b[ks] = *(const short8*)(wp1 + bo);
      }
      f32x4 acc0 = {0.f, 0.f, 0.f, 0.f};
      f32x4 acc1 = {0.f, 0.f, 0.f, 0.f};
#pragma unroll
      for (int ks = 0; ks < 4; ++ks) {
        acc0 = __builtin_amdgcn_mfma_f32_16x16x32_bf16(a0[ks], b[ks], acc0, 0, 0, 0);
        acc1 = __builtin_amdgcn_mfma_f32_16x16x32_bf16(a1[ks], b[ks], acc1, 0, 0, 0);
      }
      float twv = tw1[e * 128 + col];
      float bv  = b1[e * 128 + col];
#pragma unroll
      for (int rr = 0; rr < 4; ++rr) {
        int r0_ = lq * 4 + rr;
        int r1_ = r0_ + 16;
        float v0 = fmaxf(acc0[rr] + t0[rr] * twv + bv, 0.f);
        float v1 = fmaxf(acc1[rr] + t1[rr] * twv + bv, 0.f);
        *(unsigned short*)(hp + ((r0_ * 256 + col * 2) ^ ((r0_ & 7) << 4))) = f2bf(v0);
        *(unsigned short*)(hp + ((r1_ * 256 + col * 2) ^ ((r1_ & 7) << 4))) = f2bf(v1);
      }
    }

    // wave-local LDS fence between h1 writes and transposed reads (rule 18)
    asm volatile("s_waitcnt lgkmcnt(0)" ::: "memory");
    __builtin_amdgcn_sched_barrier(0);

#pragma unroll
    for (int ks = 0; ks < 4; ++ks) {
      int off0 = (lr * 256 + ks * 64 + lq * 16) ^ ((lr & 7) << 4);
      int off1 = ((16 + lr) * 256 + ks * 64 + lq * 16) ^ ((lr & 7) << 4);
      a0[ks] = *(const short8*)(hp + off0);
      a1[ks] = *(const short8*)(hp + off1);
    }

    // ===== layer 2 + fused layer 3: o += relu(h1@W2 + t*tw2 + b2) * W3 =====
    const float* W3e = W3 + e * 128;
    float o0[4] = {0.f, 0.f, 0.f, 0.f};
    float o1[4] = {0.f, 0.f, 0.f, 0.f};
#pragma unroll
    for (int ct = 0; ct < 8; ++ct) {
      int col = ct * 16 + lr;
      short8 b[4];
#pragma unroll
      for (int ks = 0; ks < 4; ++ks) {
        int bo = (col * 256 + ks * 64 + lq * 16) ^ ((lr & 7) << 4);
        b[ks] = *(const short8*)(wp2 + bo);
      }
      f32x4 acc0 = {0.f, 0.f, 0.f, 0.f};
      f32x4 acc1 = {0.f, 0.f, 0.f, 0.f};
#pragma unroll
      for (int ks = 0; ks < 4; ++ks) {
        acc0 = __builtin_amdgcn_mfma_f32_16x16x32_bf16(a0[ks], b[ks], acc0, 0, 0, 0);
        acc1 = __builtin_amdgcn_mfma_f32_16x16x32_bf16(a1[ks], b[ks], acc1, 0, 0, 0);
      }
      float twv = tw2[e * 128 + col];
      float bv  = b2[e * 128 + col];
      float w3v = W3e[col];
#pragma unroll
      for (int rr = 0; rr < 4; ++rr) {
        float v0 = fmaxf(acc0[rr] + t0[rr] * twv + bv, 0.f);
        float v1 = fmaxf(acc1[rr] + t1[rr] * twv + bv, 0.f);
        o0[rr] += v0 * w3v;
        o1[rr] += v1 * w3v;
      }
    }

    // reduce over 16 cols held across lanes lr=0..15 (xor stays in-group)
#pragma unroll
    for (int rr = 0; rr < 4; ++rr) {
      float s0 = o0[rr], s1 = o1[rr];
      s0 += __shfl_xor(s0, 1);  s1 += __shfl_xor(s1, 1);
      s0 += __shfl_xor(s0, 2);  s1 += __shfl_xor(s1, 2);
      s0 += __shfl_xor(s0, 4);  s1 += __shfl_xor(s1, 4);
      s0 += __shfl_xor(s0, 8);  s1 += __shfl_xor(s1, 8);
      o0[rr] = s0;  o1[rr] = s1;
    }

    if (lr == 0) {
      float tw3v = tw3[e];
      float b3v  = b3[e];
#pragma unroll
      for (int rr = 0; rr < 4; ++rr) {
        if (base + lq * 4 + rr < n)
          out[ro0[rr]] = o0[rr] + t0[rr] * tw3v + b3v;
        if (base + 16 + lq * 4 + rr < n)
          out[ro1[rr]] = o1[rr] + t1[rr] * tw3v + b3v;
      }
    }
  }
}

extern "C" void kernel_launch(void* const* d_in, const int* in_sizes, int n_in,
                              void* d_out, int out_size, void* d_ws, size_t ws_size,
                              hipStream_t stream) {
  const float* x   = (const float*)d_in[0];
  const float* W1  = (const float*)d_in[1];
  const float* tw1 = (const float*)d_in[2];
  const float* b1  = (const float*)d_in[3];
  const float* W2  = (const float*)d_in[4];
  const float* tw2 = (const float*)d_in[5];
  const float* b2  = (const float*)d_in[6];
  const float* W3  = (const float*)d_in[7];
  const float* tw3 = (const float*)d_in[8];
  const float* b3  = (const float*)d_in[9];
  float* out = (float*)d_out;

  char* ws = (char*)d_ws;
  int*   cnt  = (int*)ws;                                        // 256 B
  int*   ridb = (int*)(ws + 256);                                // 5*CAP*4
  float* tcb  = (float*)(ws + 256 + (size_t)NE * CAP * 4);       // 5*CAP*4
  unsigned short* xc = (unsigned short*)(ws + 256 + (size_t)NE * CAP * 8);  // 5*CAP*256 B
  unsigned short* Wswz = (unsigned short*)(ws + 256 + (size_t)NE * CAP * 8
                                           + (size_t)NE * CAP * 256);       // 320 KB

  hipMemsetAsync(cnt, 0, NE * sizeof(int), stream);
  convw<<<640, 256, 0, stream>>>(W1, W2, Wswz);
  classify_compact<<<NROWS / 64, 256, 0, stream>>>(x, xc, tcb, ridb, cnt);
  mlp<<<NE * BPE, 512, 0, stream>>>(xc, tcb, ridb, cnt, Wswz,
                                    tw1, b1, tw2, b2, W3, tw3, b3, out);
}

// Round 8
// 110.361 us; speedup vs baseline: 1.4954x; 1.0164x over previous
//
#include <hip/hip_runtime.h>

#define NROWS 262144
#define NE 5
#define CAP 57344                 // per-expert capacity (mean 52429, ~24 sigma)
#define BPE 51                    // mlp blocks per expert (5*51 = 255 blocks)
#define CHUNK 256                 // rows per mlp block-iteration (8 waves x 32)
#define CPAD 16                   // counter stride in ints -> 64B, one line each

typedef __attribute__((ext_vector_type(8))) short short8;
typedef __attribute__((ext_vector_type(8))) unsigned short ushort8;
typedef __attribute__((ext_vector_type(4))) float f32x4;
// 16B vector load with only 4B alignment guarantee (rows start at +4B)
typedef __attribute__((ext_vector_type(4), aligned(4))) float f32x4u;

__device__ __forceinline__ unsigned short f2bf(float x) {
  unsigned u = __float_as_uint(x);
  u += 0x7FFF + ((u >> 16) & 1);   // round-to-nearest-even
  return (unsigned short)(u >> 16);
}

// ---- kernel 1: W1,W2 -> bf16 in the SWIZZLED LDS-image layout --------------
// Element (col=j, k) lives at byte ((j*256 + k*2) ^ ((j&7)<<4)) within its
// layer so mlp can memcpy into LDS and read conflict-free b128 fragments.
__global__ __launch_bounds__(256) void convw(const float* __restrict__ W1,
                                             const float* __restrict__ W2,
                                             unsigned short* __restrict__ Wswz) {
  int idx = blockIdx.x * 256 + threadIdx.x;       // 0 .. 163839
  int which = idx / 81920;
  int rem = idx % 81920;
  int e = rem / 16384;
  int jk = rem % 16384;
  int j = jk >> 7;                // output col
  int k = jk & 127;               // k index
  const float* W = which ? W2 : W1;
  int byteoff = (j * 256 + k * 2) ^ ((j & 7) << 4);
  Wswz[(size_t)e * 32768 + which * 16384 + (byteoff >> 1)] =
      f2bf(W[(size_t)e * 16384 + k * 128 + j]);
}

// ---- kernel 2: classify + compact, barrier-light, high occupancy -----------
// 256 rows/block, ~1.3 KB LDS (8 blocks/CU). Thread i: gather t_i, classify,
// LDS count -> one padded global atomic per expert -> dst. Copy phase: 4
// threads/row stream the row's 128 floats as 8 independent float4u, write
// 256 B contiguous bf16 per row. 4 cheap barriers, ~32 loads in flight/thread.
__global__ __launch_bounds__(256) void classify2(
    const float* __restrict__ x,
    unsigned short* __restrict__ xc, float* __restrict__ tcb,
    int* __restrict__ ridb, int* __restrict__ cnt) {
  __shared__ int lcS[NE];
  __shared__ int gbS[NE];
  __shared__ int dstS[256];

  int tid = threadIdx.x;
  int r0 = blockIdx.x * 256;

  if (tid < NE) lcS[tid] = 0;
  float t = x[(size_t)(r0 + tid) * 129];          // 1 gather load, all in flight
  int e = (t >= 0.2f) + (t >= 0.4f) + (t >= 0.6f) + (t >= 0.8f);
  __syncthreads();
  int lpos = atomicAdd(&lcS[e], 1);
  __syncthreads();
  if (tid < NE) gbS[tid] = atomicAdd(&cnt[tid * CPAD], lcS[tid]);
  __syncthreads();
  int d = e * CAP + min(gbS[e] + lpos, CAP - 1);
  dstS[tid] = d;
  tcb[d] = t;
  ridb[d] = r0 + tid;
  __syncthreads();

  int sub = tid & 3;
#pragma unroll
  for (int p = 0; p < 4; ++p) {
    int row = p * 64 + (tid >> 2);
    int dd = dstS[row];
    const float* src = x + (size_t)(r0 + row) * 129 + 1 + sub * 32;
    f32x4u v[8];
#pragma unroll
    for (int q = 0; q < 8; ++q) v[q] = *(const f32x4u*)(src + q * 4);
    ushort8* dp = (ushort8*)(xc + (size_t)dd * 128 + sub * 32);
#pragma unroll
    for (int c2 = 0; c2 < 4; ++c2) {
      ushort8 pk;
#pragma unroll
      for (int jj = 0; jj < 4; ++jj) {
        pk[jj]     = f2bf(v[2 * c2][jj]);
        pk[4 + jj] = f2bf(v[2 * c2 + 1][jj]);
      }
      dp[c2] = pk;
    }
  }
}

// ---- kernel 3: per-expert MLP, weights resident in LDS ---------------------
// 512 threads = 8 waves (2/SIMD), LDS = 64KB weights + 64KB h1 -> 1 block/CU.
__global__ __launch_bounds__(512, 2) void mlp(
    const unsigned short* __restrict__ xc, const float* __restrict__ tcb,
    const int* __restrict__ ridb, const int* __restrict__ cnt,
    const unsigned short* __restrict__ Wswz,
    const float* __restrict__ tw1, const float* __restrict__ b1,
    const float* __restrict__ tw2, const float* __restrict__ b2,
    const float* __restrict__ W3, const float* __restrict__ tw3,
    const float* __restrict__ b3, float* __restrict__ out) {
  __shared__ unsigned short wl[32768];          // 64 KB: W1 swz | W2 swz
  __shared__ unsigned short h1[8][32 * 128];    // 8 KB per wave, swizzled

  int tid = threadIdx.x;
  int e = blockIdx.x / BPE;
  int bi = blockIdx.x % BPE;
  int n = min(cnt[e * CPAD], CAP);

  // stage this expert's weights into LDS (4096 ushort8, 8 per thread)
  {
    const ushort8* wsrc = (const ushort8*)(Wswz + (size_t)e * 32768);
    ushort8* wdst = (ushort8*)wl;
#pragma unroll
    for (int i = 0; i < 8; ++i) wdst[i * 512 + tid] = wsrc[i * 512 + tid];
  }
  __syncthreads();

  int wave = tid >> 6;
  int lane = tid & 63;
  int lr = lane & 15;          // A-row-in-16 / D-col / B-col-in-16
  int lq = lane >> 4;          // k-quad / D-row-quad

  const char* wp1 = (const char*)wl;
  const char* wp2 = (const char*)wl + 32768;
  char* hp = (char*)h1[wave];
  const unsigned short* xce = xc + (size_t)e * CAP * 128;
  const float* tce = tcb + (size_t)e * CAP;
  const int* ride = ridb + (size_t)e * CAP;

  int nchunk = (n + CHUNK - 1) / CHUNK;
  for (int c = bi; c < nchunk; c += BPE) {
    int base = c * CHUNK + wave * 32;
    if (base >= n) continue;

    // 32 t values + row ids, coalesced (dup on lanes>=32)
    int ci = min(base + (lane & 31), n - 1);
    float tv = tce[ci];
    int rv = ride[ci];

    // A fragments from contiguous bf16 tile (8 independent 16B loads)
    int row0 = min(base + lr, n - 1);
    int row1 = min(base + 16 + lr, n - 1);
    short8 a0[4], a1[4];
#pragma unroll
    for (int ks = 0; ks < 4; ++ks) {
      a0[ks] = *(const short8*)(xce + (size_t)row0 * 128 + ks * 32 + lq * 8);
      a1[ks] = *(const short8*)(xce + (size_t)row1 * 128 + ks * 32 + lq * 8);
    }

    float t0[4], t1[4];
    int ro0[4], ro1[4];
#pragma unroll
    for (int rr = 0; rr < 4; ++rr) {
      t0[rr] = __shfl(tv, lq * 4 + rr);
      t1[rr] = __shfl(tv, 16 + lq * 4 + rr);
      ro0[rr] = __shfl(rv, lq * 4 + rr);
      ro1[rr] = __shfl(rv, 16 + lq * 4 + rr);
    }

    // ===== layer 1: h1 = relu(f@W1 + t*tw1 + b1) -> per-wave LDS ===========
#pragma unroll
    for (int ct = 0; ct < 8; ++ct) {
      int col = ct * 16 + lr;
      short8 b[4];
#pragma unroll
      for (int ks = 0; ks < 4; ++ks) {
        int bo = (col * 256 + ks * 64 + lq * 16) ^ ((lr & 7) << 4);
        b[ks] = *(const short8*)(wp1 + bo);
      }
      f32x4 acc0 = {0.f, 0.f, 0.f, 0.f};
      f32x4 acc1 = {0.f, 0.f, 0.f, 0.f};
#pragma unroll
      for (int ks = 0; ks < 4; ++ks) {
        acc0 = __builtin_amdgcn_mfma_f32_16x16x32_bf16(a0[ks], b[ks], acc0, 0, 0, 0);
        acc1 = __builtin_amdgcn_mfma_f32_16x16x32_bf16(a1[ks], b[ks], acc1, 0, 0, 0);
      }
      float twv = tw1[e * 128 + col];
      float bv  = b1[e * 128 + col];
#pragma unroll
      for (int rr = 0; rr < 4; ++rr) {
        int r0_ = lq * 4 + rr;
        int r1_ = r0_ + 16;
        float v0 = fmaxf(acc0[rr] + t0[rr] * twv + bv, 0.f);
        float v1 = fmaxf(acc1[rr] + t1[rr] * twv + bv, 0.f);
        *(unsigned short*)(hp + ((r0_ * 256 + col * 2) ^ ((r0_ & 7) << 4))) = f2bf(v0);
        *(unsigned short*)(hp + ((r1_ * 256 + col * 2) ^ ((r1_ & 7) << 4))) = f2bf(v1);
      }
    }

    // wave-local LDS fence between h1 writes and transposed reads (rule 18)
    asm volatile("s_waitcnt lgkmcnt(0)" ::: "memory");
    __builtin_amdgcn_sched_barrier(0);

#pragma unroll
    for (int ks = 0; ks < 4; ++ks) {
      int off0 = (lr * 256 + ks * 64 + lq * 16) ^ ((lr & 7) << 4);
      int off1 = ((16 + lr) * 256 + ks * 64 + lq * 16) ^ ((lr & 7) << 4);
      a0[ks] = *(const short8*)(hp + off0);
      a1[ks] = *(const short8*)(hp + off1);
    }

    // ===== layer 2 + fused layer 3: o += relu(h1@W2 + t*tw2 + b2) * W3 =====
    const float* W3e = W3 + e * 128;
    float o0[4] = {0.f, 0.f, 0.f, 0.f};
    float o1[4] = {0.f, 0.f, 0.f, 0.f};
#pragma unroll
    for (int ct = 0; ct < 8; ++ct) {
      int col = ct * 16 + lr;
      short8 b[4];
#pragma unroll
      for (int ks = 0; ks < 4; ++ks) {
        int bo = (col * 256 + ks * 64 + lq * 16) ^ ((lr & 7) << 4);
        b[ks] = *(const short8*)(wp2 + bo);
      }
      f32x4 acc0 = {0.f, 0.f, 0.f, 0.f};
      f32x4 acc1 = {0.f, 0.f, 0.f, 0.f};
#pragma unroll
      for (int ks = 0; ks < 4; ++ks) {
        acc0 = __builtin_amdgcn_mfma_f32_16x16x32_bf16(a0[ks], b[ks], acc0, 0, 0, 0);
        acc1 = __builtin_amdgcn_mfma_f32_16x16x32_bf16(a1[ks], b[ks], acc1, 0, 0, 0);
      }
      float twv = tw2[e * 128 + col];
      float bv  = b2[e * 128 + col];
      float w3v = W3e[col];
#pragma unroll
      for (int rr = 0; rr < 4; ++rr) {
        float v0 = fmaxf(acc0[rr] + t0[rr] * twv + bv, 0.f);
        float v1 = fmaxf(acc1[rr] + t1[rr] * twv + bv, 0.f);
        o0[rr] += v0 * w3v;
        o1[rr] += v1 * w3v;
      }
    }

    // reduce over 16 cols held across lanes lr=0..15 (xor stays in-group)
#pragma unroll
    for (int rr = 0; rr < 4; ++rr) {
      float s0 = o0[rr], s1 = o1[rr];
      s0 += __shfl_xor(s0, 1);  s1 += __shfl_xor(s1, 1);
      s0 += __shfl_xor(s0, 2);  s1 += __shfl_xor(s1, 2);
      s0 += __shfl_xor(s0, 4);  s1 += __shfl_xor(s1, 4);
      s0 += __shfl_xor(s0, 8);  s1 += __shfl_xor(s1, 8);
      o0[rr] = s0;  o1[rr] = s1;
    }

    if (lr == 0) {
      float tw3v = tw3[e];
      float b3v  = b3[e];
#pragma unroll
      for (int rr = 0; rr < 4; ++rr) {
        if (base + lq * 4 + rr < n)
          out[ro0[rr]] = o0[rr] + t0[rr] * tw3v + b3v;
        if (base + 16 + lq * 4 + rr < n)
          out[ro1[rr]] = o1[rr] + t1[rr] * tw3v + b3v;
      }
    }
  }
}

extern "C" void kernel_launch(void* const* d_in, const int* in_sizes, int n_in,
                              void* d_out, int out_size, void* d_ws, size_t ws_size,
                              hipStream_t stream) {
  const float* x   = (const float*)d_in[0];
  const float* W1  = (const float*)d_in[1];
  const float* tw1 = (const float*)d_in[2];
  const float* b1  = (const float*)d_in[3];
  const float* W2  = (const float*)d_in[4];
  const float* tw2 = (const float*)d_in[5];
  const float* b2  = (const float*)d_in[6];
  const float* W3  = (const float*)d_in[7];
  const float* tw3 = (const float*)d_in[8];
  const float* b3  = (const float*)d_in[9];
  float* out = (float*)d_out;

  char* ws = (char*)d_ws;
  int*   cnt  = (int*)ws;                                        // 1 KB (padded)
  int*   ridb = (int*)(ws + 1024);                               // 5*CAP*4
  float* tcb  = (float*)(ws + 1024 + (size_t)NE * CAP * 4);      // 5*CAP*4
  unsigned short* xc = (unsigned short*)(ws + 1024 + (size_t)NE * CAP * 8); // 5*CAP*256 B
  unsigned short* Wswz = (unsigned short*)(ws + 1024 + (size_t)NE * CAP * 8
                                           + (size_t)NE * CAP * 256);       // 320 KB

  hipMemsetAsync(cnt, 0, 1024, stream);
  convw<<<640, 256, 0, stream>>>(W1, W2, Wswz);
  classify2<<<NROWS / 256, 256, 0, stream>>>(x, xc, tcb, ridb, cnt);
  mlp<<<NE * BPE, 512, 0, stream>>>(xc, tcb, ridb, cnt, Wswz,
                                    tw1, b1, tw2, b2, W3, tw3, b3, out);
}